// Round 1
// baseline (782.152 us; speedup 1.0000x reference)
//
#include <hip/hip_runtime.h>

namespace {
constexpr int B = 1024, Q = 128, P = 32, N = 128, D = 64, K = 160;

__global__ __launch_bounds__(256) void k_meandist(
    const float* __restrict__ x, const float* __restrict__ y_pos,
    double* __restrict__ ws) {
  __shared__ float Yp[P][D];
  __shared__ float ysq[P];
  __shared__ float red[4];
  const int b = blockIdx.x, tid = threadIdx.x;
  const float* yb = y_pos + (size_t)b * P * D;
  for (int i = tid; i < P * D / 4; i += 256)
    reinterpret_cast<float4*>(&Yp[0][0])[i] = reinterpret_cast<const float4*>(yb)[i];
  __syncthreads();
  if (tid < P) {
    float s = 0.f;
    for (int d = 0; d < D; ++d) { float v = Yp[tid][d]; s = fmaf(v, v, s); }
    ysq[tid] = s;
  }
  __syncthreads();
  const int q = tid >> 1, ph = tid & 1;
  const float* xq = x + ((size_t)b * Q + q) * D;
  float acc[16];
#pragma unroll
  for (int j = 0; j < 16; ++j) acc[j] = 0.f;
  float xsq = 0.f;
#pragma unroll 1
  for (int d4 = 0; d4 < 16; ++d4) {
    float4 xv = reinterpret_cast<const float4*>(xq)[d4];
    xsq = fmaf(xv.x, xv.x, fmaf(xv.y, xv.y, fmaf(xv.z, xv.z, fmaf(xv.w, xv.w, xsq))));
#pragma unroll
    for (int j = 0; j < 16; ++j) {
      float4 yv = reinterpret_cast<const float4*>(&Yp[ph * 16 + j][0])[d4];
      acc[j] = fmaf(xv.x, yv.x, fmaf(xv.y, yv.y, fmaf(xv.z, yv.z, fmaf(xv.w, yv.w, acc[j]))));
    }
  }
  float dsum = 0.f;
#pragma unroll
  for (int j = 0; j < 16; ++j) {
    float d2 = xsq + ysq[ph * 16 + j] - 2.f * acc[j];
    dsum += sqrtf(fmaxf(d2, 0.f));
  }
#pragma unroll
  for (int m = 1; m < 64; m <<= 1) dsum += __shfl_xor(dsum, m);
  if ((tid & 63) == 0) red[tid >> 6] = dsum;
  __syncthreads();
  if (tid == 0)
    atomicAdd(ws, (double)(red[0] + red[1] + red[2] + red[3]));
}

__global__ __launch_bounds__(256) void k_drift(
    const float* __restrict__ x, const float* __restrict__ y_pos,
    const float* __restrict__ y_neg, double* __restrict__ ws) {
  __shared__ float Y[K][D];     // rows 0..127: y_neg, 128..159: y_pos (40 KB)
  __shared__ float ysq[K];
  __shared__ float cs[K];       // column sums of e
  __shared__ double redd[4];
  const int b = blockIdx.x, tid = threadIdx.x;
  const float* ynb = y_neg + (size_t)b * N * D;
  const float* ypb = y_pos + (size_t)b * P * D;
  for (int i = tid; i < N * D / 4; i += 256)
    reinterpret_cast<float4*>(&Y[0][0])[i] = reinterpret_cast<const float4*>(ynb)[i];
  for (int i = tid; i < P * D / 4; i += 256)
    reinterpret_cast<float4*>(&Y[N][0])[i] = reinterpret_cast<const float4*>(ypb)[i];
  __syncthreads();
  if (tid < K) {
    float s = 0.f;
    for (int d = 0; d < D; ++d) { float v = Y[tid][d]; s = fmaf(v, v, s); }
    ysq[tid] = s;
  }
  __syncthreads();

  const int q = tid >> 1;      // 2 threads per q-row
  const int kh = tid & 1;      // which 80-wide k half this thread owns
  const int kbase = kh * 80;
  const int dh = kh;           // which 32-wide d half of drift this thread owns
  const float* xq = x + ((size_t)b * Q + q) * D;

  // ---- distance: dreg[j] = dist[q][kbase+j], kept in registers ----
  float dreg[80];
#pragma unroll
  for (int j = 0; j < 80; ++j) dreg[j] = 0.f;
  float xsq = 0.f;
#pragma unroll 1
  for (int d4 = 0; d4 < 16; ++d4) {
    float4 xv = reinterpret_cast<const float4*>(xq)[d4];
    xsq = fmaf(xv.x, xv.x, fmaf(xv.y, xv.y, fmaf(xv.z, xv.z, fmaf(xv.w, xv.w, xsq))));
#pragma unroll
    for (int j = 0; j < 80; ++j) {
      float4 yv = reinterpret_cast<const float4*>(&Y[kbase + j][0])[d4];
      dreg[j] = fmaf(xv.x, yv.x, fmaf(xv.y, yv.y, fmaf(xv.z, yv.z, fmaf(xv.w, yv.w, dreg[j]))));
    }
  }
#pragma unroll
  for (int j = 0; j < 80; ++j) {
    float d2 = xsq + ysq[kbase + j] - 2.f * dreg[j];
    dreg[j] = sqrtf(fmaxf(d2, 0.f));
  }

  const float mean_dist = (float)(ws[0] / ((double)B * Q * P));
  const float base_t[3] = {0.1f, 0.5f, 1.0f};

  float drift[32];
#pragma unroll
  for (int i = 0; i < 32; ++i) drift[i] = 0.f;

  const int qoff = q & 31;  // stagger for conflict-free LDS atomics

  for (int it = 0; it < 3; ++it) {
    const float t = fmaxf(base_t[it] * mean_dist, 1e-6f);
    const float inv_t = 1.0f / t;

    __syncthreads();              // protect cs from previous temp's readers
    if (tid < K) cs[tid] = 0.f;
    __syncthreads();

    // pass 1: row sums (registers+shfl) and column sums (LDS atomics)
    float rs_part = 0.f;
#pragma unroll 1
    for (int j = 0; j < 80; ++j) {
      int jj = j + qoff; if (jj >= 80) jj -= 80;
      float e = expf(fmaxf(-dreg[jj] * inv_t, -80.f));
      rs_part += e;
      atomicAdd(&cs[kbase + jj], e);
    }
    const float rs = rs_part + __shfl_xor(rs_part, 1);
    __syncthreads();

    // pass 2: s_neg / s_pos for this q-row
    float pn = 0.f, pp = 0.f;
#pragma unroll 1
    for (int j = 0; j < 80; ++j) {
      int k = kbase + j;
      float e = expf(fmaxf(-dreg[j] * inv_t, -80.f));
      float a = e * rsqrtf(fmaxf(rs * cs[k], 1e-12f));
      if (k < N) pn += a; else pp += a;
    }
    const float sn = pn + __shfl_xor(pn, 1);
    const float sp = pp + __shfl_xor(pp, 1);

    // pass 3: drift[q][dh*32 + :] += sum_k c[q][k] * Y[k][:]
#pragma unroll 2
    for (int j = 0; j < 80; ++j) {
      int k = kbase + j;
      float e = expf(fmaxf(-dreg[j] * inv_t, -80.f));
      float a = e * rsqrtf(fmaxf(rs * cs[k], 1e-12f));
      float c_own = (k < N) ? (-sp * a) : (sn * a);
      float part = __shfl_xor(c_own, 1);
      float c0 = kh ? part : c_own;   // coefficient for k = j (neg half)
      float c1 = kh ? c_own : part;   // coefficient for k = 80 + j
#pragma unroll
      for (int d4 = 0; d4 < 8; ++d4) {
        float4 y0 = reinterpret_cast<const float4*>(&Y[j][dh * 32])[d4];
        float4 y1 = reinterpret_cast<const float4*>(&Y[80 + j][dh * 32])[d4];
        drift[d4 * 4 + 0] = fmaf(c0, y0.x, fmaf(c1, y1.x, drift[d4 * 4 + 0]));
        drift[d4 * 4 + 1] = fmaf(c0, y0.y, fmaf(c1, y1.y, drift[d4 * 4 + 1]));
        drift[d4 * 4 + 2] = fmaf(c0, y0.z, fmaf(c1, y1.z, drift[d4 * 4 + 2]));
        drift[d4 * 4 + 3] = fmaf(c0, y0.w, fmaf(c1, y1.w, drift[d4 * 4 + 3]));
      }
    }
  }

  // loss partial: sum drift^2 (each (q,d) owned by exactly one thread)
  float ls = 0.f;
#pragma unroll
  for (int i = 0; i < 32; ++i) ls = fmaf(drift[i], drift[i], ls);
  double lsd = (double)ls;
#pragma unroll
  for (int m = 1; m < 64; m <<= 1) lsd += __shfl_xor(lsd, m);
  if ((tid & 63) == 0) redd[tid >> 6] = lsd;
  __syncthreads();
  if (tid == 0)
    atomicAdd(ws + 1, redd[0] + redd[1] + redd[2] + redd[3]);
}

__global__ void k_final(const double* __restrict__ ws, float* __restrict__ out) {
  out[0] = (float)(ws[1] / ((double)B * Q * D));
}

}  // namespace

extern "C" void kernel_launch(void* const* d_in, const int* in_sizes, int n_in,
                              void* d_out, int out_size, void* d_ws, size_t ws_size,
                              hipStream_t stream) {
  const float* x = (const float*)d_in[0];
  const float* y_pos = (const float*)d_in[1];
  const float* y_neg = (const float*)d_in[2];
  float* out = (float*)d_out;
  double* ws = (double*)d_ws;

  hipMemsetAsync(d_ws, 0, 2 * sizeof(double), stream);
  k_meandist<<<B, 256, 0, stream>>>(x, y_pos, ws);
  k_drift<<<B, 256, 0, stream>>>(x, y_pos, y_neg, ws);
  k_final<<<1, 1, 0, stream>>>(ws, out);
}

// Round 2
// 367.906 us; speedup vs baseline: 2.1260x; 2.1260x over previous
//
#include <hip/hip_runtime.h>

namespace {
constexpr int B = 1024, Q = 128, P = 32, N = 128, D = 64, K = 160;

// ---------------- mean distance over cdist(x, y_pos) ----------------
__global__ __launch_bounds__(256) void k_meandist(
    const float* __restrict__ x, const float* __restrict__ y_pos,
    double* __restrict__ ws) {
  __shared__ float Yp[P][D];
  __shared__ float ysq[P];
  __shared__ float red[4];
  const int b = blockIdx.x, tid = threadIdx.x;
  const float* yb = y_pos + (size_t)b * P * D;
  for (int i = tid; i < P * D / 4; i += 256)
    reinterpret_cast<float4*>(&Yp[0][0])[i] = reinterpret_cast<const float4*>(yb)[i];
  __syncthreads();
  if (tid < P) {
    float s = 0.f;
    for (int d = 0; d < D; ++d) { float v = Yp[tid][d]; s = fmaf(v, v, s); }
    ysq[tid] = s;
  }
  __syncthreads();
  const int q = tid >> 1, ph = tid & 1;
  const float* xq = x + ((size_t)b * Q + q) * D;
  float acc[16];
#pragma unroll
  for (int j = 0; j < 16; ++j) acc[j] = 0.f;
  float xsq = 0.f;
#pragma unroll 1
  for (int d4 = 0; d4 < 16; ++d4) {
    float4 xv = reinterpret_cast<const float4*>(xq)[d4];
    xsq = fmaf(xv.x, xv.x, fmaf(xv.y, xv.y, fmaf(xv.z, xv.z, fmaf(xv.w, xv.w, xsq))));
#pragma unroll
    for (int j = 0; j < 16; ++j) {
      float4 yv = reinterpret_cast<const float4*>(&Yp[ph * 16 + j][0])[d4];
      acc[j] = fmaf(xv.x, yv.x, fmaf(xv.y, yv.y, fmaf(xv.z, yv.z, fmaf(xv.w, yv.w, acc[j]))));
    }
  }
  float dsum = 0.f;
#pragma unroll
  for (int j = 0; j < 16; ++j) {
    float d2 = xsq + ysq[ph * 16 + j] - 2.f * acc[j];
    dsum += sqrtf(fmaxf(d2, 0.f));
  }
#pragma unroll
  for (int m = 1; m < 64; m <<= 1) dsum += __shfl_xor(dsum, m);
  if ((tid & 63) == 0) red[tid >> 6] = dsum;
  __syncthreads();
  if (tid == 0)
    atomicAdd(ws, (double)(red[0] + red[1] + red[2] + red[3]));
}

// slot swizzle for the c-slab: slot' = s + (s>>3); row = 34 float4 slots
__device__ __forceinline__ int csl(int s) { return s + (s >> 3); }

// ---------------- main fused drift kernel ----------------
// One block per batch. Producer mapping: qg = tid&15 (8 q rows), kt = tid>>4
// (10 k cols). Consumer mapping: cq = tid&15 (8 q), dgc = (tid>>4)&7 (8 d),
// kh = tid>>7 (k-half of slab). dist tile 8x10 in regs; drift tile 8x8 in regs.
__global__ __launch_bounds__(256, 2) void k_drift(
    const float* __restrict__ x, const float* __restrict__ y_pos,
    const float* __restrict__ y_neg, double* __restrict__ ws) {
  __shared__ float Yb[K * D];         // 40960 B; reused for drift-merge at end
  __shared__ float4 CS4[40 * 34];     // 21760 B; X-chunk staging, then c-slab
  __shared__ float rs_s[Q];           // row sums (also holds loss partials at end)
  __shared__ float Sp_s[Q], Sn_s[Q];
  __shared__ float cys[K];            // ysq during dist, col sums during temps

  const int b = blockIdx.x, tid = threadIdx.x;
  float4* Y4 = (float4*)Yb;

  // stage Y = [y_neg ; y_pos] (160 x 64 f32)
  const float4* yn4 = (const float4*)(y_neg + (size_t)b * N * D);
  const float4* yp4 = (const float4*)(y_pos + (size_t)b * P * D);
  for (int i = tid; i < N * D / 4; i += 256) Y4[i] = yn4[i];
  for (int i = tid; i < P * D / 4; i += 256) Y4[N * D / 4 + i] = yp4[i];
  __syncthreads();
  if (tid < K) {           // ysq (rotated column reads to spread banks)
    float s = 0.f;
#pragma unroll
    for (int c = 0; c < 16; ++c) {
      int cc = (c + tid) & 15;
      float4 v = Y4[tid * 16 + cc];
      s = fmaf(v.x, v.x, fmaf(v.y, v.y, fmaf(v.z, v.z, fmaf(v.w, v.w, s))));
    }
    cys[tid] = s;
  }

  const int qg = tid & 15, kt = tid >> 4;
  const int qb = qg * 8, kb0 = kt * 10;

  // ---- distance tile: dd[i][j] for q = qb+i, k = kb0+j ----
  float dd[8][10];
#pragma unroll
  for (int i = 0; i < 8; ++i)
#pragma unroll
    for (int j = 0; j < 10; ++j) dd[i][j] = 0.f;
  float xsq[8] = {0.f, 0.f, 0.f, 0.f, 0.f, 0.f, 0.f, 0.f};

  const float4* xg = (const float4*)(x + (size_t)b * Q * D);
#pragma unroll 1
  for (int ch = 0; ch < 4; ++ch) {
    __syncthreads();   // previous chunk consumed (ch=0: ysq writes done too)
#pragma unroll
    for (int r = 0; r < 2; ++r) {
      int g = tid + 256 * r;
      int qq = g >> 2, c4 = g & 3;
      CS4[c4 * 145 + qq + (qq >> 3)] = xg[qq * 16 + ch * 4 + c4];
    }
    __syncthreads();
#pragma unroll
    for (int d4 = 0; d4 < 4; ++d4) {
      const int dd4 = (d4 + kt) & 3;     // rotation: conflict-free Y reads
      float4 xv[8];
#pragma unroll
      for (int i = 0; i < 8; ++i) xv[i] = CS4[dd4 * 145 + 9 * qg + i];
#pragma unroll
      for (int i = 0; i < 8; ++i)
        xsq[i] = fmaf(xv[i].x, xv[i].x, fmaf(xv[i].y, xv[i].y,
                 fmaf(xv[i].z, xv[i].z, fmaf(xv[i].w, xv[i].w, xsq[i]))));
#pragma unroll
      for (int j = 0; j < 10; ++j) {
        float4 yv = Y4[(kb0 + j) * 16 + ch * 4 + dd4];
#pragma unroll
        for (int i = 0; i < 8; ++i)
          dd[i][j] = fmaf(xv[i].x, yv.x, fmaf(xv[i].y, yv.y,
                     fmaf(xv[i].z, yv.z, fmaf(xv[i].w, yv.w, dd[i][j]))));
      }
    }
  }
#pragma unroll
  for (int i = 0; i < 8; ++i)
#pragma unroll
    for (int j = 0; j < 10; ++j) {
      float d2 = xsq[i] + cys[kb0 + j] - 2.f * dd[i][j];
      dd[i][j] = sqrtf(fmaxf(d2, 0.f));
    }

  const float meand = (float)(ws[0] / ((double)B * Q * P));
  const float tb[3] = {0.1f, 0.5f, 1.0f};

  const int cq = tid & 15, dgc = (tid >> 4) & 7, kh = tid >> 7;
  float dr[8][8];
#pragma unroll
  for (int m = 0; m < 8; ++m)
#pragma unroll
    for (int n = 0; n < 8; ++n) dr[m][n] = 0.f;

#pragma unroll 1
  for (int it = 0; it < 3; ++it) {
    const float invt = 1.f / fmaxf(tb[it] * meand, 1e-6f);
    __syncthreads();
    if (tid < Q) { rs_s[tid] = 0.f; Sp_s[tid] = 0.f; Sn_s[tid] = 0.f; }
    if (tid < K) cys[tid] = 0.f;
    __syncthreads();

    // ---- pass 1: e sums -> rs (rows), cys (cols) ----
    float ers[8] = {0.f, 0.f, 0.f, 0.f, 0.f, 0.f, 0.f, 0.f};
    float ecs[10] = {0.f, 0.f, 0.f, 0.f, 0.f, 0.f, 0.f, 0.f, 0.f, 0.f};
#pragma unroll
    for (int i = 0; i < 8; ++i)
#pragma unroll
      for (int j = 0; j < 10; ++j) {
        float e = __expf(fmaxf(-dd[i][j] * invt, -80.f));
        ers[i] += e;
        ecs[j] += e;
      }
#pragma unroll
    for (int j = 0; j < 10; ++j) {   // col sums: butterfly over 16 qg lanes
      float v = ecs[j];
      v += __shfl_xor(v, 1); v += __shfl_xor(v, 2);
      v += __shfl_xor(v, 4); v += __shfl_xor(v, 8);
      ecs[j] = v;
    }
    if (qg == 0) {
#pragma unroll
      for (int j = 0; j < 10; ++j) cys[kb0 + j] = ecs[j];  // unique kt: store
    }
#pragma unroll
    for (int i = 0; i < 8; ++i) {    // row sums: reduce kt within wave, atomic across waves
      float v = ers[i];
      v += __shfl_xor(v, 16); v += __shfl_xor(v, 32);
      ers[i] = v;
    }
    if ((kt & 3) == 0) {
#pragma unroll
      for (int i = 0; i < 8; ++i) atomicAdd(&rs_s[qb + i], ers[i]);
    }
    __syncthreads();

    // ---- pass 2: affinity row sums over pos/neg ----
    float irs[8], ics[10];
#pragma unroll
    for (int i = 0; i < 8; ++i) irs[i] = rsqrtf(rs_s[qb + i]);
#pragma unroll
    for (int j = 0; j < 10; ++j) ics[j] = rsqrtf(cys[kb0 + j]);
    float sp_p[8] = {0.f, 0.f, 0.f, 0.f, 0.f, 0.f, 0.f, 0.f};
    float sn_p[8] = {0.f, 0.f, 0.f, 0.f, 0.f, 0.f, 0.f, 0.f};
#pragma unroll
    for (int i = 0; i < 8; ++i)
#pragma unroll
      for (int j = 0; j < 10; ++j) {
        float e = __expf(fmaxf(-dd[i][j] * invt, -80.f));
        float a = e * irs[i] * ics[j];
        if (kb0 + j >= N) sp_p[i] += a; else sn_p[i] += a;
      }
#pragma unroll
    for (int i = 0; i < 8; ++i) {
      float v = sp_p[i];
      v += __shfl_xor(v, 16); v += __shfl_xor(v, 32);
      sp_p[i] = v;
      float w = sn_p[i];
      w += __shfl_xor(w, 16); w += __shfl_xor(w, 32);
      sn_p[i] = w;
    }
    if ((kt & 3) == 0) {
#pragma unroll
      for (int i = 0; i < 8; ++i) {
        atomicAdd(&Sp_s[qb + i], sp_p[i]);
        atomicAdd(&Sn_s[qb + i], sn_p[i]);
      }
    }
    __syncthreads();

    float spv[8], snv[8];
#pragma unroll
    for (int i = 0; i < 8; ++i) { spv[i] = Sp_s[qb + i]; snv[i] = Sn_s[qb + i]; }

    // ---- slabs: produce signed coefficients, consume as register GEMM ----
#pragma unroll 1
    for (int s = 0; s < 4; ++s) {
      if ((kt >> 2) == s) {
#pragma unroll
        for (int j = 0; j < 10; ++j) {
          const int klocal = (kt & 3) * 10 + j;
          float c0[8];
#pragma unroll
          for (int i = 0; i < 8; ++i) {
            float e = __expf(fmaxf(-dd[i][j] * invt, -80.f));
            float a = e * irs[i] * ics[j];
            c0[i] = (kb0 + j >= N) ? a * snv[i] : -a * spv[i];
          }
          CS4[klocal * 34 + csl(2 * qg)] = make_float4(c0[0], c0[1], c0[2], c0[3]);
          CS4[klocal * 34 + csl(2 * qg + 1)] = make_float4(c0[4], c0[5], c0[6], c0[7]);
        }
      }
      __syncthreads();
      const int kbs = kh * 20;
#pragma unroll 2
      for (int kl = 0; kl < 20; ++kl) {
        const int klocal = kbs + kl;
        const int k = s * 40 + klocal;
        float4 ca = CS4[klocal * 34 + csl(2 * cq)];
        float4 cb = CS4[klocal * 34 + csl(2 * cq + 1)];
        float4 y0 = Y4[k * 16 + dgc * 2];
        float4 y1 = Y4[k * 16 + dgc * 2 + 1];
#define ACC8(m, cv)                                      \
        dr[m][0] = fmaf(cv, y0.x, dr[m][0]);             \
        dr[m][1] = fmaf(cv, y0.y, dr[m][1]);             \
        dr[m][2] = fmaf(cv, y0.z, dr[m][2]);             \
        dr[m][3] = fmaf(cv, y0.w, dr[m][3]);             \
        dr[m][4] = fmaf(cv, y1.x, dr[m][4]);             \
        dr[m][5] = fmaf(cv, y1.y, dr[m][5]);             \
        dr[m][6] = fmaf(cv, y1.z, dr[m][6]);             \
        dr[m][7] = fmaf(cv, y1.w, dr[m][7]);
        ACC8(0, ca.x) ACC8(1, ca.y) ACC8(2, ca.z) ACC8(3, ca.w)
        ACC8(4, cb.x) ACC8(5, cb.y) ACC8(6, cb.z) ACC8(7, cb.w)
#undef ACC8
      }
      __syncthreads();
    }
  }

  // ---- merge kh partners (via freed Y space) and reduce loss ----
  float4* FB = Y4;    // [16][128] float4 stripes: conflict-free both sides
  if (kh == 1) {
    const int t1 = tid - 128;
#pragma unroll
    for (int sfl = 0; sfl < 16; ++sfl) {
      const int m = sfl >> 1, hf = (sfl & 1) * 4;
      FB[sfl * 128 + t1] = make_float4(dr[m][hf], dr[m][hf + 1], dr[m][hf + 2], dr[m][hf + 3]);
    }
  }
  __syncthreads();
  float total = 0.f;
  if (kh == 0) {
#pragma unroll
    for (int sfl = 0; sfl < 16; ++sfl) {
      const int m = sfl >> 1, hf = (sfl & 1) * 4;
      float4 v = FB[sfl * 128 + tid];
      float a0 = dr[m][hf] + v.x;
      float a1 = dr[m][hf + 1] + v.y;
      float a2 = dr[m][hf + 2] + v.z;
      float a3 = dr[m][hf + 3] + v.w;
      total = fmaf(a0, a0, total);
      total = fmaf(a1, a1, total);
      total = fmaf(a2, a2, total);
      total = fmaf(a3, a3, total);
    }
#pragma unroll
    for (int msk = 1; msk < 64; msk <<= 1) total += __shfl_xor(total, msk);
  }
  __syncthreads();          // rs_s reuse as reduction scratch
  if (tid == 0) rs_s[0] = total;
  if (tid == 64) rs_s[1] = total;
  __syncthreads();
  if (tid == 0) atomicAdd(ws + 1, (double)rs_s[0] + (double)rs_s[1]);
}

__global__ void k_final(const double* __restrict__ ws, float* __restrict__ out) {
  out[0] = (float)(ws[1] / ((double)B * Q * D));
}

}  // namespace

extern "C" void kernel_launch(void* const* d_in, const int* in_sizes, int n_in,
                              void* d_out, int out_size, void* d_ws, size_t ws_size,
                              hipStream_t stream) {
  const float* x = (const float*)d_in[0];
  const float* y_pos = (const float*)d_in[1];
  const float* y_neg = (const float*)d_in[2];
  float* out = (float*)d_out;
  double* ws = (double*)d_ws;

  hipMemsetAsync(d_ws, 0, 2 * sizeof(double), stream);
  k_meandist<<<B, 256, 0, stream>>>(x, y_pos, ws);
  k_drift<<<B, 256, 0, stream>>>(x, y_pos, y_neg, ws);
  k_final<<<1, 1, 0, stream>>>(ws, out);
}